// Round 1
// baseline (415.291 us; speedup 1.0000x reference)
//
#include <hip/hip_runtime.h>

typedef _Float16 f16;
typedef _Float16 f16x8 __attribute__((ext_vector_type(8)));
typedef _Float16 f16x4 __attribute__((ext_vector_type(4)));
typedef float f32x4 __attribute__((ext_vector_type(4)));
typedef unsigned int u32;
typedef unsigned int u32x4 __attribute__((ext_vector_type(4)));

#define MFMA16(a, b, c) __builtin_amdgcn_mfma_f32_16x16x32_f16(a, b, c, 0, 0, 0)

// ---------------------------------------------------------------- prep ----
__global__ __launch_bounds__(256) void prep_kernel(
    const float* __restrict__ Wq, const float* __restrict__ Wk,
    const float* __restrict__ Wv, const float* __restrict__ Wp,
    const float* __restrict__ bq, const float* __restrict__ bk,
    const float* __restrict__ bv,
    f16* __restrict__ Wqkv, f16* __restrict__ Wph, float* __restrict__ bqkv)
{
    int i = blockIdx.x * 256 + threadIdx.x;
    if (i < 786432) {
        int r = i >> 9, c = i & 511;
        const float* src = (r < 512) ? Wq : (r < 1024) ? Wk : Wv;
        Wqkv[i] = (f16)src[(r & 511) * 512 + c];
    } else if (i < 786432 + 262144) {
        int j = i - 786432;
        Wph[j] = (f16)Wp[j];
    } else if (i < 786432 + 262144 + 1536) {
        int j = i - (786432 + 262144);
        bqkv[j] = (j < 512) ? bq[j] : (j < 1024) ? bk[j - 512] : bv[j - 1024];
    }
}

// ------------------------------------------------------------ QKV GEMM ----
// C[m,n] = sum_c X[m,c] * W[n,c] + bias[n]; scatter into partitioned Q/K/V.
__global__ __launch_bounds__(256) void qkv_gemm(
    const float* __restrict__ X, const f16* __restrict__ W,
    const float* __restrict__ bias,
    f16* __restrict__ Qp, f16* __restrict__ Kp, f16* __restrict__ Vp)
{
    __shared__ __align__(16) f16 As[128 * 72];
    __shared__ __align__(16) f16 Bs[128 * 72];
    const int tid = threadIdx.x;
    const int lane = tid & 63, wid = tid >> 6;
    const int g = lane >> 4, l15 = lane & 15;
    const int wr = wid >> 1, wc = wid & 1;
    const int brow = blockIdx.x * 128;
    const int bn = blockIdx.y;  // 0..11 (N tile of 128)

    f32x4 acc[4][4] = {};

    for (int step = 0; step < 8; ++step) {
        const int k0 = step * 64;
        // stage A: 128x64 fp32 -> fp16 LDS (stride 72 to dodge bank conflicts)
        #pragma unroll
        for (int it = 0; it < 8; ++it) {
            int idx = it * 256 + tid;
            int row = idx >> 4, seg = idx & 15;
            f32x4 xv = *(const f32x4*)(X + (size_t)(brow + row) * 512 + k0 + seg * 4);
            f16x4 hv = { (f16)xv[0], (f16)xv[1], (f16)xv[2], (f16)xv[3] };
            *(f16x4*)&As[row * 72 + seg * 4] = hv;
        }
        // stage B: 128x64 fp16
        #pragma unroll
        for (int it = 0; it < 4; ++it) {
            int idx = it * 256 + tid;
            int row = idx >> 3, seg = idx & 7;
            f16x8 wv = *(const f16x8*)(W + (size_t)(bn * 128 + row) * 512 + k0 + seg * 8);
            *(f16x8*)&Bs[row * 72 + seg * 8] = wv;
        }
        __syncthreads();
        #pragma unroll
        for (int kk = 0; kk < 2; ++kk) {
            f16x8 a[4], b[4];
            #pragma unroll
            for (int m = 0; m < 4; ++m)
                a[m] = *(const f16x8*)&As[(wr * 64 + m * 16 + l15) * 72 + kk * 32 + g * 8];
            #pragma unroll
            for (int n = 0; n < 4; ++n)
                b[n] = *(const f16x8*)&Bs[(wc * 64 + n * 16 + l15) * 72 + kk * 32 + g * 8];
            #pragma unroll
            for (int m = 0; m < 4; ++m)
                #pragma unroll
                for (int n = 0; n < 4; ++n)
                    acc[m][n] = MFMA16(a[m], b[n], acc[m][n]);
        }
        __syncthreads();
    }

    // epilogue: C/D layout col = lane&15, row = (lane>>4)*4 + reg
    const int which = bn >> 2, head = bn & 3;
    f16* dst = (which == 0) ? Qp : (which == 1) ? Kp : Vp;
    #pragma unroll
    for (int m = 0; m < 4; ++m) {
        #pragma unroll
        for (int j = 0; j < 4; ++j) {
            int gm = brow + wr * 64 + m * 16 + g * 4 + j;  // token index
            int t_ = gm / 6480, rem = gm % 6480;
            int hh = rem / 108, ww = rem % 108;
            int win = (hh / 5) * 12 + (ww / 9);
            int s = t_ * 45 + (hh % 5) * 9 + (ww % 9);
            size_t obase = ((size_t)((win * 4 + head) * 360 + s)) * 128;
            #pragma unroll
            for (int n = 0; n < 4; ++n) {
                int cidx = wc * 64 + n * 16 + l15;
                float v = acc[m][n][j] + bias[bn * 128 + cidx];
                dst[obase + cidx] = (f16)v;
            }
        }
    }
}

// ----------------------------------------------------------- attention ----
// One block per (win, head). 8 waves x 48 q-rows (padded to 384).
__global__ __launch_bounds__(512) void attn_kernel(
    const f16* __restrict__ Qp, const f16* __restrict__ Kp,
    const f16* __restrict__ Vp, f16* __restrict__ AO)
{
    __shared__ __align__(16) f16 Kl[64 * 136];   // K tile, padded stride
    __shared__ __align__(16) f16 Vt[128 * 72];   // V tile transposed [ch][k]
    __shared__ __align__(16) f16 Pl[384 * 72];   // P round-trip [q][k]

    const int tid = threadIdx.x;
    const int lane = tid & 63, wid = tid >> 6;
    const int g = lane >> 4, l15 = lane & 15;
    const int wh = blockIdx.x;
    const int win = wh >> 2, head = wh & 3;
    const int base = wh * 46080;  // 360*128

    const float SC2 = 0.08838834764831845f * 1.4426950408889634f;  // scale*log2e

    // Q fragments in registers: 48 rows x 128 ch per wave
    f16x8 qf[3][4];
    #pragma unroll
    for (int qi = 0; qi < 3; ++qi)
        #pragma unroll
        for (int c4 = 0; c4 < 4; ++c4)
            qf[qi][c4] = *(const f16x8*)(Qp + base + (wid * 48 + qi * 16 + l15) * 128 + c4 * 32 + g * 8);

    f32x4 o[3][8] = {};
    float m_r[3] = { -1e30f, -1e30f, -1e30f };
    float l_r[3] = { 0.f, 0.f, 0.f };

    for (int kt = 0; kt < 6; ++kt) {
        // --- stage K tile [64][128] linearly (padded stride 136)
        #pragma unroll
        for (int it = 0; it < 2; ++it) {
            int idx = it * 512 + tid;
            int krow = idx >> 4, seg = idx & 15;
            f16x8 kv = *(const f16x8*)(Kp + base + (kt * 64 + krow) * 128 + seg * 8);
            *(f16x8*)&Kl[krow * 136 + seg * 8] = kv;
        }
        // --- stage V tile transposed: [ch][k], zero-fill k >= 360
        {
            const u32* Vb = (const u32*)(Vp + base);
            int chp = (tid & 63) * 2;
            int kb = wid;  // 0..7 -> k block of 8
            u32 d[8];
            #pragma unroll
            for (int i = 0; i < 8; ++i) {
                int kg = kt * 64 + kb * 8 + i;
                d[i] = (kg < 360) ? Vb[kg * 64 + (chp >> 1)] : 0u;
            }
            u32x4 lo, hi;
            #pragma unroll
            for (int jj = 0; jj < 4; ++jj) {
                lo[jj] = (d[2 * jj] & 0xffffu) | (d[2 * jj + 1] << 16);
                hi[jj] = (d[2 * jj] >> 16) | (d[2 * jj + 1] & 0xffff0000u);
            }
            *(u32x4*)&Vt[chp * 72 + kb * 8] = lo;
            *(u32x4*)&Vt[(chp + 1) * 72 + kb * 8] = hi;
        }
        __syncthreads();

        // --- S^T = K · Q^T : C[k,q], lane holds col q = lane&15, rows k = g*4+j
        f32x4 sc[4][3] = {};
        #pragma unroll
        for (int c4 = 0; c4 < 4; ++c4) {
            f16x8 ka[4];
            #pragma unroll
            for (int kf = 0; kf < 4; ++kf)
                ka[kf] = *(const f16x8*)&Kl[(kf * 16 + l15) * 136 + c4 * 32 + g * 8];
            #pragma unroll
            for (int kf = 0; kf < 4; ++kf)
                #pragma unroll
                for (int qi = 0; qi < 3; ++qi)
                    sc[kf][qi] = MFMA16(ka[kf], qf[qi][c4], sc[kf][qi]);
        }
        // mask pad keys (only last tile)
        if (kt == 5) {
            #pragma unroll
            for (int kf = 0; kf < 4; ++kf)
                #pragma unroll
                for (int j = 0; j < 4; ++j)
                    if (320 + kf * 16 + g * 4 + j >= 360) {
                        #pragma unroll
                        for (int qi = 0; qi < 3; ++qi) sc[kf][qi][j] = -1e30f;
                    }
        }

        // --- online softmax; P -> LDS
        #pragma unroll
        for (int qi = 0; qi < 3; ++qi) {
            float mx = -1e30f;
            #pragma unroll
            for (int kf = 0; kf < 4; ++kf)
                #pragma unroll
                for (int j = 0; j < 4; ++j)
                    mx = fmaxf(mx, sc[kf][qi][j]);
            mx = fmaxf(mx, __shfl_xor(mx, 16));
            mx = fmaxf(mx, __shfl_xor(mx, 32));
            float mnew = fmaxf(m_r[qi], mx);
            float r = exp2f((m_r[qi] - mnew) * SC2);
            m_r[qi] = mnew;
            float psum = 0.f;
            #pragma unroll
            for (int kf = 0; kf < 4; ++kf) {
                f16x4 pv;
                #pragma unroll
                for (int j = 0; j < 4; ++j) {
                    float p = exp2f((sc[kf][qi][j] - mnew) * SC2);
                    psum += p;
                    pv[j] = (f16)p;
                }
                *(f16x4*)&Pl[(wid * 48 + qi * 16 + l15) * 72 + kf * 16 + g * 4] = pv;
            }
            psum += __shfl_xor(psum, 16);
            psum += __shfl_xor(psum, 32);
            l_r[qi] = l_r[qi] * r + psum;
            // rescale O: r lives at lanes keyed by q=lane&15; O rows are g*4+j
            #pragma unroll
            for (int j = 0; j < 4; ++j) {
                float rj = __shfl(r, g * 4 + j);
                #pragma unroll
                for (int chf = 0; chf < 8; ++chf)
                    o[qi][chf][j] *= rj;
            }
        }

        // --- PV: O[q,ch] += P[q,k] * V[k,ch]
        #pragma unroll
        for (int kc = 0; kc < 2; ++kc) {
            f16x8 pa[3], vb[8];
            #pragma unroll
            for (int qi = 0; qi < 3; ++qi)
                pa[qi] = *(const f16x8*)&Pl[(wid * 48 + qi * 16 + l15) * 72 + kc * 32 + g * 8];
            #pragma unroll
            for (int chf = 0; chf < 8; ++chf)
                vb[chf] = *(const f16x8*)&Vt[(chf * 16 + l15) * 72 + kc * 32 + g * 8];
            #pragma unroll
            for (int qi = 0; qi < 3; ++qi)
                #pragma unroll
                for (int chf = 0; chf < 8; ++chf)
                    o[qi][chf] = MFMA16(pa[qi], vb[chf], o[qi][chf]);
        }
        __syncthreads();
    }

    // --- epilogue: normalize, un-partition, store fp16 AO[token][512]
    #pragma unroll
    for (int qi = 0; qi < 3; ++qi) {
        #pragma unroll
        for (int j = 0; j < 4; ++j) {
            float lj = __shfl(l_r[qi], g * 4 + j);
            float inv = 1.0f / lj;
            int s = wid * 48 + qi * 16 + g * 4 + j;
            if (s < 360) {
                int t_ = s / 45, s45 = s % 45;
                int hh = (win / 12) * 5 + s45 / 9;
                int ww = (win % 12) * 9 + s45 % 9;
                int mm = t_ * 6480 + hh * 108 + ww;
                #pragma unroll
                for (int chf = 0; chf < 8; ++chf) {
                    int col = head * 128 + chf * 16 + l15;
                    AO[(size_t)mm * 512 + col] = (f16)(o[qi][chf][j] * inv);
                }
            }
        }
    }
}

// ----------------------------------------------------------- out proj ----
__global__ __launch_bounds__(256) void proj_gemm(
    const f16* __restrict__ A, const f16* __restrict__ W,
    const float* __restrict__ bias, float* __restrict__ out)
{
    __shared__ __align__(16) f16 As[128 * 72];
    __shared__ __align__(16) f16 Bs[128 * 72];
    const int tid = threadIdx.x;
    const int lane = tid & 63, wid = tid >> 6;
    const int g = lane >> 4, l15 = lane & 15;
    const int wr = wid >> 1, wc = wid & 1;
    const int brow = blockIdx.x * 128;
    const int bcol = blockIdx.y * 128;

    f32x4 acc[4][4] = {};

    for (int step = 0; step < 8; ++step) {
        const int k0 = step * 64;
        #pragma unroll
        for (int it = 0; it < 4; ++it) {
            int idx = it * 256 + tid;
            int row = idx >> 3, seg = idx & 7;
            f16x8 av = *(const f16x8*)(A + (size_t)(brow + row) * 512 + k0 + seg * 8);
            *(f16x8*)&As[row * 72 + seg * 8] = av;
        }
        #pragma unroll
        for (int it = 0; it < 4; ++it) {
            int idx = it * 256 + tid;
            int row = idx >> 3, seg = idx & 7;
            f16x8 wv = *(const f16x8*)(W + (size_t)(bcol + row) * 512 + k0 + seg * 8);
            *(f16x8*)&Bs[row * 72 + seg * 8] = wv;
        }
        __syncthreads();
        #pragma unroll
        for (int kk = 0; kk < 2; ++kk) {
            f16x8 a[4], b[4];
            #pragma unroll
            for (int m = 0; m < 4; ++m)
                a[m] = *(const f16x8*)&As[(wr * 64 + m * 16 + l15) * 72 + kk * 32 + g * 8];
            #pragma unroll
            for (int n = 0; n < 4; ++n)
                b[n] = *(const f16x8*)&Bs[(wc * 64 + n * 16 + l15) * 72 + kk * 32 + g * 8];
            #pragma unroll
            for (int m = 0; m < 4; ++m)
                #pragma unroll
                for (int n = 0; n < 4; ++n)
                    acc[m][n] = MFMA16(a[m], b[n], acc[m][n]);
        }
        __syncthreads();
    }

    #pragma unroll
    for (int m = 0; m < 4; ++m)
        #pragma unroll
        for (int j = 0; j < 4; ++j) {
            int gm = brow + wr * 64 + m * 16 + g * 4 + j;
            #pragma unroll
            for (int n = 0; n < 4; ++n) {
                int gn = bcol + wc * 64 + n * 16 + l15;
                out[(size_t)gm * 512 + gn] = acc[m][n][j] + bias[gn];
            }
        }
}

// -------------------------------------------------------------- launch ----
extern "C" void kernel_launch(void* const* d_in, const int* in_sizes, int n_in,
                              void* d_out, int out_size, void* d_ws, size_t ws_size,
                              hipStream_t stream)
{
    (void)in_sizes; (void)n_in; (void)out_size; (void)ws_size;
    const float* x  = (const float*)d_in[0];
    const float* Wq = (const float*)d_in[1];
    const float* bq = (const float*)d_in[2];
    const float* Wk = (const float*)d_in[3];
    const float* bk = (const float*)d_in[4];
    const float* Wv = (const float*)d_in[5];
    const float* bv = (const float*)d_in[6];
    const float* Wp = (const float*)d_in[7];
    const float* bp = (const float*)d_in[8];

    // workspace layout (fp16 elems): Qp/Kp/Vp [576][360][128], AO [51840][512]
    f16* Qp   = (f16*)d_ws;
    f16* Kp   = Qp + 26542080;
    f16* Vp   = Kp + 26542080;
    f16* AO   = Vp + 26542080;
    f16* Wqkv = AO + 26542080;
    f16* Wph  = Wqkv + 786432;
    float* bqkv = (float*)(Wph + 262144);

    prep_kernel<<<4102, 256, 0, stream>>>(Wq, Wk, Wv, Wp, bq, bk, bv, Wqkv, Wph, bqkv);
    qkv_gemm<<<dim3(405, 12), 256, 0, stream>>>(x, Wqkv, bqkv, Qp, Kp, Vp);
    attn_kernel<<<576, 512, 0, stream>>>(Qp, Kp, Vp, AO);
    proj_gemm<<<dim3(405, 4), 256, 0, stream>>>(AO, Wph, bp, (float*)d_out);
}

// Round 2
// 360.434 us; speedup vs baseline: 1.1522x; 1.1522x over previous
//
#include <hip/hip_runtime.h>

typedef _Float16 f16;
typedef _Float16 f16x8 __attribute__((ext_vector_type(8)));
typedef _Float16 f16x4 __attribute__((ext_vector_type(4)));
typedef float f32x4 __attribute__((ext_vector_type(4)));
typedef unsigned int u32;
typedef unsigned int u32x4 __attribute__((ext_vector_type(4)));

#define MFMA16(a, b, c) __builtin_amdgcn_mfma_f32_16x16x32_f16(a, b, c, 0, 0, 0)

__device__ __forceinline__ void async_copy16(f16* lds, const f16* g) {
    __builtin_amdgcn_global_load_lds(
        (const __attribute__((address_space(1))) unsigned int*)g,
        (__attribute__((address_space(3))) unsigned int*)lds,
        16, 0, 0);
}

// ---------------------------------------------------------------- prep ----
__global__ __launch_bounds__(256) void prep_kernel(
    const float* __restrict__ Wq, const float* __restrict__ Wk,
    const float* __restrict__ Wv, const float* __restrict__ Wp,
    const float* __restrict__ bq, const float* __restrict__ bk,
    const float* __restrict__ bv,
    f16* __restrict__ Wqkv, f16* __restrict__ Wph, float* __restrict__ bqkv)
{
    int i = blockIdx.x * 256 + threadIdx.x;
    if (i < 786432) {
        int r = i >> 9, c = i & 511;
        const float* src = (r < 512) ? Wq : (r < 1024) ? Wk : Wv;
        Wqkv[i] = (f16)src[(r & 511) * 512 + c];
    } else if (i < 786432 + 262144) {
        int j = i - 786432;
        Wph[j] = (f16)Wp[j];
    } else if (i < 786432 + 262144 + 1536) {
        int j = i - (786432 + 262144);
        bqkv[j] = (j < 512) ? bq[j] : (j < 1024) ? bk[j - 512] : bv[j - 1024];
    }
}

// ---------------------------------------------------------- convert x ----
__global__ __launch_bounds__(256) void convert_x(
    const float* __restrict__ x, f16* __restrict__ xh)
{
    int i = blockIdx.x * 256 + threadIdx.x;   // 3,317,760 total, each does 8
    f32x4 a = *(const f32x4*)(x + (size_t)i * 8);
    f32x4 b = *(const f32x4*)(x + (size_t)i * 8 + 4);
    f16x8 h = { (f16)a[0], (f16)a[1], (f16)a[2], (f16)a[3],
                (f16)b[0], (f16)b[1], (f16)b[2], (f16)b[3] };
    *(f16x8*)(xh + (size_t)i * 8) = h;
}

// ------------------------------------------------------------ QKV GEMM ----
// C[m,n] = sum_c Xh[m,c] * W[n,c] + bias[n]; scatter into partitioned Q/K/V.
// grid: (12 N-tiles, 405 M-tiles) so x-adjacent blocks share the A panel.
__global__ __launch_bounds__(256) void qkv_gemm(
    const f16* __restrict__ Xh, const f16* __restrict__ W,
    const float* __restrict__ bias,
    f16* __restrict__ Qp, f16* __restrict__ Kp, f16* __restrict__ Vp)
{
    __shared__ __align__(16) f16 As[128 * 64];
    __shared__ __align__(16) f16 Bs[128 * 64];
    const int tid = threadIdx.x;
    const int lane = tid & 63, wid = tid >> 6;
    const int g = lane >> 4, l15 = lane & 15;
    const int wr = wid >> 1, wc = wid & 1;
    const int bn = blockIdx.x;              // 0..11
    const int brow = blockIdx.y * 128;

    const f16* Abase = Xh + (size_t)brow * 512;
    const f16* Bbase = W + (size_t)bn * 128 * 512;

    f32x4 acc[4][4] = {};

    for (int step = 0; step < 8; ++step) {
        const int k0 = step * 64;
        #pragma unroll
        for (int r = 0; r < 4; ++r) {
            int idx = r * 256 + tid;          // 0..1023
            int row = idx >> 3, ch = idx & 7;
            async_copy16(As + idx * 8, Abase + (size_t)row * 512 + k0 + ch * 8);
            async_copy16(Bs + idx * 8, Bbase + (size_t)row * 512 + k0 + ch * 8);
        }
        asm volatile("s_waitcnt vmcnt(0)" ::: "memory");
        __syncthreads();
        #pragma unroll
        for (int kk = 0; kk < 2; ++kk) {
            f16x8 a[4], b[4];
            #pragma unroll
            for (int m = 0; m < 4; ++m)
                a[m] = *(const f16x8*)&As[(wr * 64 + m * 16 + l15) * 64 + kk * 32 + g * 8];
            #pragma unroll
            for (int n = 0; n < 4; ++n)
                b[n] = *(const f16x8*)&Bs[(wc * 64 + n * 16 + l15) * 64 + kk * 32 + g * 8];
            #pragma unroll
            for (int m = 0; m < 4; ++m)
                #pragma unroll
                for (int n = 0; n < 4; ++n)
                    acc[m][n] = MFMA16(a[m], b[n], acc[m][n]);
        }
        __syncthreads();
    }

    // epilogue: C/D layout col = lane&15, row = (lane>>4)*4 + reg
    const int which = bn >> 2, head = bn & 3;
    f16* dst = (which == 0) ? Qp : (which == 1) ? Kp : Vp;
    #pragma unroll
    for (int m = 0; m < 4; ++m) {
        #pragma unroll
        for (int j = 0; j < 4; ++j) {
            int gm = brow + wr * 64 + m * 16 + g * 4 + j;  // token index
            int t_ = gm / 6480, rem = gm % 6480;
            int hh = rem / 108, ww = rem % 108;
            int win = (hh / 5) * 12 + (ww / 9);
            int s = t_ * 45 + (hh % 5) * 9 + (ww % 9);
            size_t obase = ((size_t)((win * 4 + head) * 360 + s)) * 128;
            #pragma unroll
            for (int n = 0; n < 4; ++n) {
                int cidx = wc * 64 + n * 16 + l15;
                float v = acc[m][n][j] + bias[bn * 128 + cidx];
                dst[obase + cidx] = (f16)v;
            }
        }
    }
}

// ----------------------------------------------------------- attention ----
// One block per (win, head). 8 waves x 48 q-rows (padded to 384).
__global__ __launch_bounds__(512) void attn_kernel(
    const f16* __restrict__ Qp, const f16* __restrict__ Kp,
    const f16* __restrict__ Vp, f16* __restrict__ AO)
{
    __shared__ __align__(16) f16 Kl[64 * 136];   // K tile, padded stride
    __shared__ __align__(16) f16 Vt[128 * 72];   // V tile transposed [ch][k]
    __shared__ __align__(16) f16 Pl[384 * 72];   // P round-trip [q][k]

    const int tid = threadIdx.x;
    const int lane = tid & 63, wid = tid >> 6;
    const int g = lane >> 4, l15 = lane & 15;
    const int wh = blockIdx.x;
    const int win = wh >> 2, head = wh & 3;
    const int base = wh * 46080;  // 360*128

    const float SC2 = 0.08838834764831845f * 1.4426950408889634f;  // scale*log2e

    // Q fragments in registers: 48 rows x 128 ch per wave
    f16x8 qf[3][4];
    #pragma unroll
    for (int qi = 0; qi < 3; ++qi)
        #pragma unroll
        for (int c4 = 0; c4 < 4; ++c4)
            qf[qi][c4] = *(const f16x8*)(Qp + base + (wid * 48 + qi * 16 + l15) * 128 + c4 * 32 + g * 8);

    f32x4 o[3][8] = {};
    float m_r[3] = { -1e30f, -1e30f, -1e30f };
    float l_r[3] = { 0.f, 0.f, 0.f };

    for (int kt = 0; kt < 6; ++kt) {
        // --- stage K tile [64][128] linearly (padded stride 136)
        #pragma unroll
        for (int it = 0; it < 2; ++it) {
            int idx = it * 512 + tid;
            int krow = idx >> 4, seg = idx & 15;
            f16x8 kv = *(const f16x8*)(Kp + base + (kt * 64 + krow) * 128 + seg * 8);
            *(f16x8*)&Kl[krow * 136 + seg * 8] = kv;
        }
        // --- stage V tile transposed: [ch][k], zero-fill k >= 360
        {
            const u32* Vb = (const u32*)(Vp + base);
            int chp = (tid & 63) * 2;
            int kb = wid;  // 0..7 -> k block of 8
            u32 d[8];
            #pragma unroll
            for (int i = 0; i < 8; ++i) {
                int kg = kt * 64 + kb * 8 + i;
                d[i] = (kg < 360) ? Vb[kg * 64 + (chp >> 1)] : 0u;
            }
            u32x4 lo, hi;
            #pragma unroll
            for (int jj = 0; jj < 4; ++jj) {
                lo[jj] = (d[2 * jj] & 0xffffu) | (d[2 * jj + 1] << 16);
                hi[jj] = (d[2 * jj] >> 16) | (d[2 * jj + 1] & 0xffff0000u);
            }
            *(u32x4*)&Vt[chp * 72 + kb * 8] = lo;
            *(u32x4*)&Vt[(chp + 1) * 72 + kb * 8] = hi;
        }
        __syncthreads();

        // --- S^T = K · Q^T : C[k,q], lane holds col q = lane&15, rows k = g*4+j
        f32x4 sc[4][3] = {};
        #pragma unroll
        for (int c4 = 0; c4 < 4; ++c4) {
            f16x8 ka[4];
            #pragma unroll
            for (int kf = 0; kf < 4; ++kf)
                ka[kf] = *(const f16x8*)&Kl[(kf * 16 + l15) * 136 + c4 * 32 + g * 8];
            #pragma unroll
            for (int kf = 0; kf < 4; ++kf)
                #pragma unroll
                for (int qi = 0; qi < 3; ++qi)
                    sc[kf][qi] = MFMA16(ka[kf], qf[qi][c4], sc[kf][qi]);
        }
        // mask pad keys (only last tile)
        if (kt == 5) {
            #pragma unroll
            for (int kf = 0; kf < 4; ++kf)
                #pragma unroll
                for (int j = 0; j < 4; ++j)
                    if (320 + kf * 16 + g * 4 + j >= 360) {
                        #pragma unroll
                        for (int qi = 0; qi < 3; ++qi) sc[kf][qi][j] = -1e30f;
                    }
        }

        // --- online softmax; P -> LDS
        #pragma unroll
        for (int qi = 0; qi < 3; ++qi) {
            float mx = -1e30f;
            #pragma unroll
            for (int kf = 0; kf < 4; ++kf)
                #pragma unroll
                for (int j = 0; j < 4; ++j)
                    mx = fmaxf(mx, sc[kf][qi][j]);
            mx = fmaxf(mx, __shfl_xor(mx, 16));
            mx = fmaxf(mx, __shfl_xor(mx, 32));
            float mnew = fmaxf(m_r[qi], mx);
            float r = exp2f((m_r[qi] - mnew) * SC2);
            m_r[qi] = mnew;
            float psum = 0.f;
            #pragma unroll
            for (int kf = 0; kf < 4; ++kf) {
                f16x4 pv;
                #pragma unroll
                for (int j = 0; j < 4; ++j) {
                    float p = exp2f((sc[kf][qi][j] - mnew) * SC2);
                    psum += p;
                    pv[j] = (f16)p;
                }
                *(f16x4*)&Pl[(wid * 48 + qi * 16 + l15) * 72 + kf * 16 + g * 4] = pv;
            }
            psum += __shfl_xor(psum, 16);
            psum += __shfl_xor(psum, 32);
            l_r[qi] = l_r[qi] * r + psum;
            // rescale O: r lives at lanes keyed by q=lane&15; O rows are g*4+j
            #pragma unroll
            for (int j = 0; j < 4; ++j) {
                float rj = __shfl(r, g * 4 + j);
                #pragma unroll
                for (int chf = 0; chf < 8; ++chf)
                    o[qi][chf][j] *= rj;
            }
        }

        // --- PV: O[q,ch] += P[q,k] * V[k,ch]
        #pragma unroll
        for (int kc = 0; kc < 2; ++kc) {
            f16x8 pa[3], vb[8];
            #pragma unroll
            for (int qi = 0; qi < 3; ++qi)
                pa[qi] = *(const f16x8*)&Pl[(wid * 48 + qi * 16 + l15) * 72 + kc * 32 + g * 8];
            #pragma unroll
            for (int chf = 0; chf < 8; ++chf)
                vb[chf] = *(const f16x8*)&Vt[(chf * 16 + l15) * 72 + kc * 32 + g * 8];
            #pragma unroll
            for (int qi = 0; qi < 3; ++qi)
                #pragma unroll
                for (int chf = 0; chf < 8; ++chf)
                    o[qi][chf] = MFMA16(pa[qi], vb[chf], o[qi][chf]);
        }
        __syncthreads();
    }

    // --- epilogue: normalize, un-partition, store fp16 AO[token][512]
    #pragma unroll
    for (int qi = 0; qi < 3; ++qi) {
        #pragma unroll
        for (int j = 0; j < 4; ++j) {
            float lj = __shfl(l_r[qi], g * 4 + j);
            float inv = 1.0f / lj;
            int s = wid * 48 + qi * 16 + g * 4 + j;
            if (s < 360) {
                int t_ = s / 45, s45 = s % 45;
                int hh = (win / 12) * 5 + s45 / 9;
                int ww = (win % 12) * 9 + s45 % 9;
                int mm = t_ * 6480 + hh * 108 + ww;
                #pragma unroll
                for (int chf = 0; chf < 8; ++chf) {
                    int col = head * 128 + chf * 16 + l15;
                    AO[(size_t)mm * 512 + col] = (f16)(o[qi][chf][j] * inv);
                }
            }
        }
    }
}

// ----------------------------------------------------------- out proj ----
// grid: (4 N-tiles, 405 M-tiles)
__global__ __launch_bounds__(256) void proj_gemm(
    const f16* __restrict__ A, const f16* __restrict__ W,
    const float* __restrict__ bias, float* __restrict__ out)
{
    __shared__ __align__(16) f16 As[128 * 64];
    __shared__ __align__(16) f16 Bs[128 * 64];
    const int tid = threadIdx.x;
    const int lane = tid & 63, wid = tid >> 6;
    const int g = lane >> 4, l15 = lane & 15;
    const int wr = wid >> 1, wc = wid & 1;
    const int bcol = blockIdx.x * 128;
    const int brow = blockIdx.y * 128;

    const f16* Abase = A + (size_t)brow * 512;
    const f16* Bbase = W + (size_t)bcol * 512;

    f32x4 acc[4][4] = {};

    for (int step = 0; step < 8; ++step) {
        const int k0 = step * 64;
        #pragma unroll
        for (int r = 0; r < 4; ++r) {
            int idx = r * 256 + tid;
            int row = idx >> 3, ch = idx & 7;
            async_copy16(As + idx * 8, Abase + (size_t)row * 512 + k0 + ch * 8);
            async_copy16(Bs + idx * 8, Bbase + (size_t)row * 512 + k0 + ch * 8);
        }
        asm volatile("s_waitcnt vmcnt(0)" ::: "memory");
        __syncthreads();
        #pragma unroll
        for (int kk = 0; kk < 2; ++kk) {
            f16x8 a[4], b[4];
            #pragma unroll
            for (int m = 0; m < 4; ++m)
                a[m] = *(const f16x8*)&As[(wr * 64 + m * 16 + l15) * 64 + kk * 32 + g * 8];
            #pragma unroll
            for (int n = 0; n < 4; ++n)
                b[n] = *(const f16x8*)&Bs[(wc * 64 + n * 16 + l15) * 64 + kk * 32 + g * 8];
            #pragma unroll
            for (int m = 0; m < 4; ++m)
                #pragma unroll
                for (int n = 0; n < 4; ++n)
                    acc[m][n] = MFMA16(a[m], b[n], acc[m][n]);
        }
        __syncthreads();
    }

    #pragma unroll
    for (int m = 0; m < 4; ++m)
        #pragma unroll
        for (int j = 0; j < 4; ++j) {
            int gm = brow + wr * 64 + m * 16 + g * 4 + j;
            #pragma unroll
            for (int n = 0; n < 4; ++n) {
                int gn = bcol + wc * 64 + n * 16 + l15;
                out[(size_t)gm * 512 + gn] = acc[m][n][j] + bias[gn];
            }
        }
}

// -------------------------------------------------------------- launch ----
extern "C" void kernel_launch(void* const* d_in, const int* in_sizes, int n_in,
                              void* d_out, int out_size, void* d_ws, size_t ws_size,
                              hipStream_t stream)
{
    (void)in_sizes; (void)n_in; (void)out_size; (void)ws_size;
    const float* x  = (const float*)d_in[0];
    const float* Wq = (const float*)d_in[1];
    const float* bq = (const float*)d_in[2];
    const float* Wk = (const float*)d_in[3];
    const float* bk = (const float*)d_in[4];
    const float* Wv = (const float*)d_in[5];
    const float* bv = (const float*)d_in[6];
    const float* Wp = (const float*)d_in[7];
    const float* bp = (const float*)d_in[8];

    // workspace layout (fp16 elems): Qp/Kp/Vp [576][360][128], AO [51840][512]
    // xh (fp16 X) aliases AO: dead before attn_kernel overwrites AO.
    f16* Qp   = (f16*)d_ws;
    f16* Kp   = Qp + 26542080;
    f16* Vp   = Kp + 26542080;
    f16* AO   = Vp + 26542080;
    f16* xh   = AO;
    f16* Wqkv = AO + 26542080;
    f16* Wph  = Wqkv + 786432;
    float* bqkv = (float*)(Wph + 262144);

    prep_kernel<<<4102, 256, 0, stream>>>(Wq, Wk, Wv, Wp, bq, bk, bv, Wqkv, Wph, bqkv);
    convert_x<<<12960, 256, 0, stream>>>(x, xh);
    qkv_gemm<<<dim3(12, 405), 256, 0, stream>>>(xh, Wqkv, bqkv, Qp, Kp, Vp);
    attn_kernel<<<576, 512, 0, stream>>>(Qp, Kp, Vp, AO);
    proj_gemm<<<dim3(4, 405), 256, 0, stream>>>(AO, Wph, bp, (float*)d_out);
}

// Round 3
// 319.107 us; speedup vs baseline: 1.3014x; 1.1295x over previous
//
#include <hip/hip_runtime.h>

typedef _Float16 f16;
typedef _Float16 f16x8 __attribute__((ext_vector_type(8)));
typedef _Float16 f16x4 __attribute__((ext_vector_type(4)));
typedef float f32x4 __attribute__((ext_vector_type(4)));
typedef unsigned int u32;
typedef unsigned int u32x4 __attribute__((ext_vector_type(4)));

#define MFMA16(a, b, c) __builtin_amdgcn_mfma_f32_16x16x32_f16(a, b, c, 0, 0, 0)

__device__ __forceinline__ void async_copy16(f16* lds, const f16* g) {
    __builtin_amdgcn_global_load_lds(
        (const __attribute__((address_space(1))) unsigned int*)g,
        (__attribute__((address_space(3))) unsigned int*)lds,
        16, 0, 0);
}

// ---------------------------------------------------------------- prep ----
__global__ __launch_bounds__(256) void prep_kernel(
    const float* __restrict__ Wq, const float* __restrict__ Wk,
    const float* __restrict__ Wv, const float* __restrict__ Wp,
    const float* __restrict__ bq, const float* __restrict__ bk,
    const float* __restrict__ bv,
    f16* __restrict__ Wqkv, f16* __restrict__ Wph, float* __restrict__ bqkv,
    int* __restrict__ tokmap)
{
    int i = blockIdx.x * 256 + threadIdx.x;
    if (i < 786432) {
        int r = i >> 9, c = i & 511;
        const float* src = (r < 512) ? Wq : (r < 1024) ? Wk : Wv;
        Wqkv[i] = (f16)src[(r & 511) * 512 + c];
    } else if (i < 786432 + 262144) {
        int j = i - 786432;
        Wph[j] = (f16)Wp[j];
    } else if (i < 786432 + 262144 + 1536) {
        int j = i - (786432 + 262144);
        bqkv[j] = (j < 512) ? bq[j] : (j < 1024) ? bk[j - 512] : bv[j - 1024];
    } else if (i < 786432 + 262144 + 1536 + 51840) {
        int j = i - (786432 + 262144 + 1536);
        int t_ = j / 6480, rem = j % 6480;
        int hh = rem / 108, ww = rem % 108;
        int win = (hh / 5) * 12 + (ww / 9);
        int s = t_ * 45 + (hh % 5) * 9 + (ww % 9);
        tokmap[j] = win * 1440 + s;   // obase/128 (head 0)
    }
}

// ---------------------------------------------------------- convert x ----
__global__ __launch_bounds__(256) void convert_x(
    const float* __restrict__ x, f16* __restrict__ xh)
{
    int i = blockIdx.x * 256 + threadIdx.x;   // 3,317,760 total, each does 8
    f32x4 a = *(const f32x4*)(x + (size_t)i * 8);
    f32x4 b = *(const f32x4*)(x + (size_t)i * 8 + 4);
    f16x8 h = { (f16)a[0], (f16)a[1], (f16)a[2], (f16)a[3],
                (f16)b[0], (f16)b[1], (f16)b[2], (f16)b[3] };
    *(f16x8*)(xh + (size_t)i * 8) = h;
}

// ------------------------------------------------------------ QKV GEMM ----
// C[m,n] = sum_c Xh[m,c] * W[n,c] + bias[n]; scatter into partitioned Q/K/V.
// 1D grid 4860, bijective XCD swizzle; logical wg = bm*12 + bn so the 12
// N-tiles sharing an A-panel run on one XCD (L2 reuse).
// Double-buffered LDS: stage(t+1) issued BEFORE compute(t).
__global__ __launch_bounds__(256) void qkv_gemm(
    const f16* __restrict__ Xh, const f16* __restrict__ W,
    const float* __restrict__ bias, const int* __restrict__ tokmap,
    f16* __restrict__ Qp, f16* __restrict__ Kp, f16* __restrict__ Vp)
{
    __shared__ __align__(16) f16 As[2][128 * 64];
    __shared__ __align__(16) f16 Bs[2][128 * 64];
    const int tid = threadIdx.x;
    const int lane = tid & 63, wid = tid >> 6;
    const int g = lane >> 4, l15 = lane & 15;
    const int wr = wid >> 1, wc = wid & 1;

    // bijective XCD chunk remap (nwg=4860, q=607, r=4)
    const int orig = blockIdx.x;
    const int xcd = orig & 7;
    const int wg = (xcd < 4 ? xcd * 608 : 2432 + (xcd - 4) * 607) + (orig >> 3);
    const int bn = wg % 12;
    const int brow = (wg / 12) * 128;

    const f16* Abase = Xh + (size_t)brow * 512;
    const f16* Bbase = W + (size_t)bn * 128 * 512;

    f32x4 acc[4][4] = {};

    // stage helper: 128x64 A tile + 128x64 B tile, 16B async per lane
    #define QKV_STAGE(buf, step)                                              \
        {                                                                     \
            const int k0_ = (step) * 64;                                      \
            _Pragma("unroll")                                                 \
            for (int rr = 0; rr < 4; ++rr) {                                  \
                int idx = rr * 256 + tid;                                     \
                int row = idx >> 3, ch = idx & 7;                             \
                async_copy16(&As[buf][idx * 8],                               \
                             Abase + (size_t)row * 512 + k0_ + ch * 8);       \
                async_copy16(&Bs[buf][idx * 8],                               \
                             Bbase + (size_t)row * 512 + k0_ + ch * 8);       \
            }                                                                 \
        }

    QKV_STAGE(0, 0);
    asm volatile("s_waitcnt vmcnt(0)" ::: "memory");
    __syncthreads();

    int cur = 0;
    for (int step = 0; step < 8; ++step) {
        if (step < 7) QKV_STAGE(cur ^ 1, step + 1);
        #pragma unroll
        for (int kk = 0; kk < 2; ++kk) {
            f16x8 a[4], b[4];
            #pragma unroll
            for (int m = 0; m < 4; ++m)
                a[m] = *(const f16x8*)&As[cur][(wr * 64 + m * 16 + l15) * 64 + kk * 32 + g * 8];
            #pragma unroll
            for (int n = 0; n < 4; ++n)
                b[n] = *(const f16x8*)&Bs[cur][(wc * 64 + n * 16 + l15) * 64 + kk * 32 + g * 8];
            #pragma unroll
            for (int m = 0; m < 4; ++m)
                #pragma unroll
                for (int n = 0; n < 4; ++n)
                    acc[m][n] = MFMA16(a[m], b[n], acc[m][n]);
        }
        asm volatile("s_waitcnt vmcnt(0)" ::: "memory");
        __syncthreads();
        cur ^= 1;
    }
    #undef QKV_STAGE

    // epilogue: C/D layout col = lane&15, row = (lane>>4)*4 + reg
    const int which = bn >> 2, head = bn & 3;
    f16* dst = (which == 0) ? Qp : (which == 1) ? Kp : Vp;
    #pragma unroll
    for (int m = 0; m < 4; ++m) {
        #pragma unroll
        for (int j = 0; j < 4; ++j) {
            int gm = brow + wr * 64 + m * 16 + g * 4 + j;  // token index
            size_t obase = ((size_t)(tokmap[gm] + head * 360)) * 128;
            #pragma unroll
            for (int n = 0; n < 4; ++n) {
                int cidx = wc * 64 + n * 16 + l15;
                float v = acc[m][n][j] + bias[bn * 128 + cidx];
                dst[obase + cidx] = (f16)v;
            }
        }
    }
}

// ----------------------------------------------------------- attention ----
// One block per (win, head). 8 waves x 48 q-rows (padded to 384).
__global__ __launch_bounds__(512) void attn_kernel(
    const f16* __restrict__ Qp, const f16* __restrict__ Kp,
    const f16* __restrict__ Vp, f16* __restrict__ AO)
{
    __shared__ __align__(16) f16 Kl[64 * 136];   // K tile, padded stride
    __shared__ __align__(16) f16 Vt[128 * 72];   // V tile transposed [ch][k]
    __shared__ __align__(16) f16 Pl[384 * 72];   // P round-trip [q][k]

    const int tid = threadIdx.x;
    const int lane = tid & 63, wid = tid >> 6;
    const int g = lane >> 4, l15 = lane & 15;
    const int wh = blockIdx.x;
    const int win = wh >> 2, head = wh & 3;
    const int base = wh * 46080;  // 360*128

    const float SC2 = 0.08838834764831845f * 1.4426950408889634f;  // scale*log2e

    // Q fragments in registers: 48 rows x 128 ch per wave
    f16x8 qf[3][4];
    #pragma unroll
    for (int qi = 0; qi < 3; ++qi)
        #pragma unroll
        for (int c4 = 0; c4 < 4; ++c4)
            qf[qi][c4] = *(const f16x8*)(Qp + base + (wid * 48 + qi * 16 + l15) * 128 + c4 * 32 + g * 8);

    f32x4 o[3][8] = {};
    float m_r[3] = { -1e30f, -1e30f, -1e30f };
    float l_r[3] = { 0.f, 0.f, 0.f };

    for (int kt = 0; kt < 6; ++kt) {
        // --- stage K tile [64][128] linearly (padded stride 136)
        #pragma unroll
        for (int it = 0; it < 2; ++it) {
            int idx = it * 512 + tid;
            int krow = idx >> 4, seg = idx & 15;
            f16x8 kv = *(const f16x8*)(Kp + base + (kt * 64 + krow) * 128 + seg * 8);
            *(f16x8*)&Kl[krow * 136 + seg * 8] = kv;
        }
        // --- stage V tile transposed: [ch][k], zero-fill k >= 360
        {
            const u32* Vb = (const u32*)(Vp + base);
            int chp = (tid & 63) * 2;
            int kb = wid;  // 0..7 -> k block of 8
            u32 d[8];
            #pragma unroll
            for (int i = 0; i < 8; ++i) {
                int kg = kt * 64 + kb * 8 + i;
                d[i] = (kg < 360) ? Vb[kg * 64 + (chp >> 1)] : 0u;
            }
            u32x4 lo, hi;
            #pragma unroll
            for (int jj = 0; jj < 4; ++jj) {
                lo[jj] = (d[2 * jj] & 0xffffu) | (d[2 * jj + 1] << 16);
                hi[jj] = (d[2 * jj] >> 16) | (d[2 * jj + 1] & 0xffff0000u);
            }
            *(u32x4*)&Vt[chp * 72 + kb * 8] = lo;
            *(u32x4*)&Vt[(chp + 1) * 72 + kb * 8] = hi;
        }
        __syncthreads();

        // --- S^T = K · Q^T : C[k,q], lane holds col q = lane&15, rows k = g*4+j
        f32x4 sc[4][3] = {};
        #pragma unroll
        for (int c4 = 0; c4 < 4; ++c4) {
            f16x8 ka[4];
            #pragma unroll
            for (int kf = 0; kf < 4; ++kf)
                ka[kf] = *(const f16x8*)&Kl[(kf * 16 + l15) * 136 + c4 * 32 + g * 8];
            #pragma unroll
            for (int kf = 0; kf < 4; ++kf)
                #pragma unroll
                for (int qi = 0; qi < 3; ++qi)
                    sc[kf][qi] = MFMA16(ka[kf], qf[qi][c4], sc[kf][qi]);
        }
        // mask pad keys (only last tile)
        if (kt == 5) {
            #pragma unroll
            for (int kf = 0; kf < 4; ++kf)
                #pragma unroll
                for (int j = 0; j < 4; ++j)
                    if (320 + kf * 16 + g * 4 + j >= 360) {
                        #pragma unroll
                        for (int qi = 0; qi < 3; ++qi) sc[kf][qi][j] = -1e30f;
                    }
        }

        // --- online softmax; P -> LDS
        #pragma unroll
        for (int qi = 0; qi < 3; ++qi) {
            float mx = -1e30f;
            #pragma unroll
            for (int kf = 0; kf < 4; ++kf)
                #pragma unroll
                for (int j = 0; j < 4; ++j)
                    mx = fmaxf(mx, sc[kf][qi][j]);
            mx = fmaxf(mx, __shfl_xor(mx, 16));
            mx = fmaxf(mx, __shfl_xor(mx, 32));
            float mnew = fmaxf(m_r[qi], mx);
            float r = exp2f((m_r[qi] - mnew) * SC2);
            m_r[qi] = mnew;
            float psum = 0.f;
            #pragma unroll
            for (int kf = 0; kf < 4; ++kf) {
                f16x4 pv;
                #pragma unroll
                for (int j = 0; j < 4; ++j) {
                    float p = exp2f((sc[kf][qi][j] - mnew) * SC2);
                    psum += p;
                    pv[j] = (f16)p;
                }
                *(f16x4*)&Pl[(wid * 48 + qi * 16 + l15) * 72 + kf * 16 + g * 4] = pv;
            }
            psum += __shfl_xor(psum, 16);
            psum += __shfl_xor(psum, 32);
            l_r[qi] = l_r[qi] * r + psum;
            // rescale O: r lives at lanes keyed by q=lane&15; O rows are g*4+j
            #pragma unroll
            for (int j = 0; j < 4; ++j) {
                float rj = __shfl(r, g * 4 + j);
                #pragma unroll
                for (int chf = 0; chf < 8; ++chf)
                    o[qi][chf][j] *= rj;
            }
        }

        // --- PV: O[q,ch] += P[q,k] * V[k,ch]
        #pragma unroll
        for (int kc = 0; kc < 2; ++kc) {
            f16x8 pa[3], vb[8];
            #pragma unroll
            for (int qi = 0; qi < 3; ++qi)
                pa[qi] = *(const f16x8*)&Pl[(wid * 48 + qi * 16 + l15) * 72 + kc * 32 + g * 8];
            #pragma unroll
            for (int chf = 0; chf < 8; ++chf)
                vb[chf] = *(const f16x8*)&Vt[(chf * 16 + l15) * 72 + kc * 32 + g * 8];
            #pragma unroll
            for (int qi = 0; qi < 3; ++qi)
                #pragma unroll
                for (int chf = 0; chf < 8; ++chf)
                    o[qi][chf] = MFMA16(pa[qi], vb[chf], o[qi][chf]);
        }
        __syncthreads();
    }

    // --- epilogue: normalize, un-partition, store fp16 AO[token][512]
    #pragma unroll
    for (int qi = 0; qi < 3; ++qi) {
        #pragma unroll
        for (int j = 0; j < 4; ++j) {
            float lj = __shfl(l_r[qi], g * 4 + j);
            float inv = 1.0f / lj;
            int s = wid * 48 + qi * 16 + g * 4 + j;
            if (s < 360) {
                int t_ = s / 45, s45 = s % 45;
                int hh = (win / 12) * 5 + s45 / 9;
                int ww = (win % 12) * 9 + s45 % 9;
                int mm = t_ * 6480 + hh * 108 + ww;
                #pragma unroll
                for (int chf = 0; chf < 8; ++chf) {
                    int col = head * 128 + chf * 16 + l15;
                    AO[(size_t)mm * 512 + col] = (f16)(o[qi][chf][j] * inv);
                }
            }
        }
    }
}

// ----------------------------------------------------------- out proj ----
// 1D grid 1620, bijective XCD swizzle; logical wg = bm*4 + bn.
__global__ __launch_bounds__(256) void proj_gemm(
    const f16* __restrict__ A, const f16* __restrict__ W,
    const float* __restrict__ bias, float* __restrict__ out)
{
    __shared__ __align__(16) f16 As[2][128 * 64];
    __shared__ __align__(16) f16 Bs[2][128 * 64];
    const int tid = threadIdx.x;
    const int lane = tid & 63, wid = tid >> 6;
    const int g = lane >> 4, l15 = lane & 15;
    const int wr = wid >> 1, wc = wid & 1;

    // bijective XCD chunk remap (nwg=1620, q=202, r=4)
    const int orig = blockIdx.x;
    const int xcd = orig & 7;
    const int wg = (xcd < 4 ? xcd * 203 : 812 + (xcd - 4) * 202) + (orig >> 3);
    const int bcol = (wg & 3) * 128;
    const int brow = (wg >> 2) * 128;

    const f16* Abase = A + (size_t)brow * 512;
    const f16* Bbase = W + (size_t)bcol * 512;

    f32x4 acc[4][4] = {};

    #define PROJ_STAGE(buf, step)                                             \
        {                                                                     \
            const int k0_ = (step) * 64;                                      \
            _Pragma("unroll")                                                 \
            for (int rr = 0; rr < 4; ++rr) {                                  \
                int idx = rr * 256 + tid;                                     \
                int row = idx >> 3, ch = idx & 7;                             \
                async_copy16(&As[buf][idx * 8],                               \
                             Abase + (size_t)row * 512 + k0_ + ch * 8);       \
                async_copy16(&Bs[buf][idx * 8],                               \
                             Bbase + (size_t)row * 512 + k0_ + ch * 8);       \
            }                                                                 \
        }

    PROJ_STAGE(0, 0);
    asm volatile("s_waitcnt vmcnt(0)" ::: "memory");
    __syncthreads();

    int cur = 0;
    for (int step = 0; step < 8; ++step) {
        if (step < 7) PROJ_STAGE(cur ^ 1, step + 1);
        #pragma unroll
        for (int kk = 0; kk < 2; ++kk) {
            f16x8 a[4], b[4];
            #pragma unroll
            for (int m = 0; m < 4; ++m)
                a[m] = *(const f16x8*)&As[cur][(wr * 64 + m * 16 + l15) * 64 + kk * 32 + g * 8];
            #pragma unroll
            for (int n = 0; n < 4; ++n)
                b[n] = *(const f16x8*)&Bs[cur][(wc * 64 + n * 16 + l15) * 64 + kk * 32 + g * 8];
            #pragma unroll
            for (int m = 0; m < 4; ++m)
                #pragma unroll
                for (int n = 0; n < 4; ++n)
                    acc[m][n] = MFMA16(a[m], b[n], acc[m][n]);
        }
        asm volatile("s_waitcnt vmcnt(0)" ::: "memory");
        __syncthreads();
        cur ^= 1;
    }
    #undef PROJ_STAGE

    #pragma unroll
    for (int m = 0; m < 4; ++m)
        #pragma unroll
        for (int j = 0; j < 4; ++j) {
            int gm = brow + wr * 64 + m * 16 + g * 4 + j;
            #pragma unroll
            for (int n = 0; n < 4; ++n) {
                int gn = bcol + wc * 64 + n * 16 + l15;
                out[(size_t)gm * 512 + gn] = acc[m][n][j] + bias[gn];
            }
        }
}

// -------------------------------------------------------------- launch ----
extern "C" void kernel_launch(void* const* d_in, const int* in_sizes, int n_in,
                              void* d_out, int out_size, void* d_ws, size_t ws_size,
                              hipStream_t stream)
{
    (void)in_sizes; (void)n_in; (void)out_size; (void)ws_size;
    const float* x  = (const float*)d_in[0];
    const float* Wq = (const float*)d_in[1];
    const float* bq = (const float*)d_in[2];
    const float* Wk = (const float*)d_in[3];
    const float* bk = (const float*)d_in[4];
    const float* Wv = (const float*)d_in[5];
    const float* bv = (const float*)d_in[6];
    const float* Wp = (const float*)d_in[7];
    const float* bp = (const float*)d_in[8];

    // workspace layout (fp16 elems): Qp/Kp/Vp [576][360][128], AO [51840][512]
    // xh (fp16 X) aliases AO: dead before attn_kernel overwrites AO.
    f16* Qp   = (f16*)d_ws;
    f16* Kp   = Qp + 26542080;
    f16* Vp   = Kp + 26542080;
    f16* AO   = Vp + 26542080;
    f16* xh   = AO;
    f16* Wqkv = AO + 26542080;
    f16* Wph  = Wqkv + 786432;
    float* bqkv = (float*)(Wph + 262144);
    int* tokmap = (int*)(bqkv + 1536);

    prep_kernel<<<4305, 256, 0, stream>>>(Wq, Wk, Wv, Wp, bq, bk, bv, Wqkv, Wph, bqkv, tokmap);
    convert_x<<<12960, 256, 0, stream>>>(x, xh);
    qkv_gemm<<<4860, 256, 0, stream>>>(xh, Wqkv, bqkv, tokmap, Qp, Kp, Vp);
    attn_kernel<<<576, 512, 0, stream>>>(Qp, Kp, Vp, AO);
    proj_gemm<<<1620, 256, 0, stream>>>(AO, Wph, bp, (float*)d_out);
}

// Round 4
// 305.769 us; speedup vs baseline: 1.3582x; 1.0436x over previous
//
#include <hip/hip_runtime.h>

typedef _Float16 f16;
typedef _Float16 f16x8 __attribute__((ext_vector_type(8)));
typedef _Float16 f16x4 __attribute__((ext_vector_type(4)));
typedef float f32x4 __attribute__((ext_vector_type(4)));
typedef unsigned int u32;
typedef unsigned int u32x4 __attribute__((ext_vector_type(4)));

#define MFMA16(a, b, c) __builtin_amdgcn_mfma_f32_16x16x32_f16(a, b, c, 0, 0, 0)

__device__ __forceinline__ void async_copy16(f16* lds, const f16* g) {
    __builtin_amdgcn_global_load_lds(
        (const __attribute__((address_space(1))) unsigned int*)g,
        (__attribute__((address_space(3))) unsigned int*)lds,
        16, 0, 0);
}

// ---------------------------------------------------------------- prep ----
__global__ __launch_bounds__(256) void prep_kernel(
    const float* __restrict__ Wq, const float* __restrict__ Wk,
    const float* __restrict__ Wv, const float* __restrict__ Wp,
    const float* __restrict__ bq, const float* __restrict__ bk,
    const float* __restrict__ bv,
    f16* __restrict__ Wqkv, f16* __restrict__ Wph, float* __restrict__ bqkv,
    int* __restrict__ tokmap)
{
    int i = blockIdx.x * 256 + threadIdx.x;
    if (i < 786432) {
        int r = i >> 9, c = i & 511;
        const float* src = (r < 512) ? Wq : (r < 1024) ? Wk : Wv;
        Wqkv[i] = (f16)src[(r & 511) * 512 + c];
    } else if (i < 786432 + 262144) {
        int j = i - 786432;
        Wph[j] = (f16)Wp[j];
    } else if (i < 786432 + 262144 + 1536) {
        int j = i - (786432 + 262144);
        bqkv[j] = (j < 512) ? bq[j] : (j < 1024) ? bk[j - 512] : bv[j - 1024];
    } else if (i < 786432 + 262144 + 1536 + 51840) {
        int j = i - (786432 + 262144 + 1536);
        int t_ = j / 6480, rem = j % 6480;
        int hh = rem / 108, ww = rem % 108;
        int win = (hh / 5) * 12 + (ww / 9);
        int s = t_ * 45 + (hh % 5) * 9 + (ww % 9);
        tokmap[j] = win * 1440 + s;   // obase/128 (head 0)
    }
}

// ---------------------------------------------------------- convert x ----
__global__ __launch_bounds__(256) void convert_x(
    const float* __restrict__ x, f16* __restrict__ xh)
{
    int i = blockIdx.x * 256 + threadIdx.x;   // 3,317,760 total, each does 8
    f32x4 a = *(const f32x4*)(x + (size_t)i * 8);
    f32x4 b = *(const f32x4*)(x + (size_t)i * 8 + 4);
    f16x8 h = { (f16)a[0], (f16)a[1], (f16)a[2], (f16)a[3],
                (f16)b[0], (f16)b[1], (f16)b[2], (f16)b[3] };
    *(f16x8*)(xh + (size_t)i * 8) = h;
}

// ------------------------------------------------------------ QKV GEMM ----
// C[m,n] = sum_c Xh[m,c] * W[n,c] + bias[n]; scatter into partitioned Q/K/V.
// 1D grid 4860, bijective XCD swizzle; logical wg = bm*12 + bn.
// Double-buffered LDS, stage(t+1) before compute(t).
// LDS XOR-swizzle (T2, both-sides): physical 16B slot c holds logical
// slot c^(row&7); gload_lds source pre-swizzled, ds_read applies same XOR.
__global__ __launch_bounds__(256) void qkv_gemm(
    const f16* __restrict__ Xh, const f16* __restrict__ W,
    const float* __restrict__ bias, const int* __restrict__ tokmap,
    f16* __restrict__ Qp, f16* __restrict__ Kp, f16* __restrict__ Vp)
{
    __shared__ __align__(16) f16 As[2][128 * 64];
    __shared__ __align__(16) f16 Bs[2][128 * 64];
    const int tid = threadIdx.x;
    const int lane = tid & 63, wid = tid >> 6;
    const int g = lane >> 4, l15 = lane & 15;
    const int wr = wid >> 1, wc = wid & 1;

    // bijective XCD chunk remap (nwg=4860, q=607, r=4)
    const int orig = blockIdx.x;
    const int xcd = orig & 7;
    const int wg = (xcd < 4 ? xcd * 608 : 2432 + (xcd - 4) * 607) + (orig >> 3);
    const int bn = wg % 12;
    const int brow = (wg / 12) * 128;

    const f16* Abase = Xh + (size_t)brow * 512;
    const f16* Bbase = W + (size_t)bn * 128 * 512;

    f32x4 acc[4][4] = {};

    // stage: LDS dest linear (gload_lds constraint); global source slot
    // pre-swizzled so that ds_read with the same XOR sees logical layout.
    #define QKV_STAGE(buf, step)                                              \
        {                                                                     \
            const int k0_ = (step) * 64;                                      \
            _Pragma("unroll")                                                 \
            for (int rr = 0; rr < 4; ++rr) {                                  \
                int idx = rr * 256 + tid;                                     \
                int row = idx >> 3, ch = idx & 7;                             \
                int sch = ch ^ (row & 7);                                     \
                async_copy16(&As[buf][idx * 8],                               \
                             Abase + (size_t)row * 512 + k0_ + sch * 8);      \
                async_copy16(&Bs[buf][idx * 8],                               \
                             Bbase + (size_t)row * 512 + k0_ + sch * 8);      \
            }                                                                 \
        }

    QKV_STAGE(0, 0);
    asm volatile("s_waitcnt vmcnt(0)" ::: "memory");
    __syncthreads();

    int cur = 0;
    for (int step = 0; step < 8; ++step) {
        if (step < 7) QKV_STAGE(cur ^ 1, step + 1);
        #pragma unroll
        for (int kk = 0; kk < 2; ++kk) {
            f16x8 a[4], b[4];
            #pragma unroll
            for (int m = 0; m < 4; ++m) {
                int arow = wr * 64 + m * 16 + l15;
                int acol = (kk * 4 + g) ^ (arow & 7);
                a[m] = *(const f16x8*)&As[cur][arow * 64 + acol * 8];
            }
            #pragma unroll
            for (int n = 0; n < 4; ++n) {
                int brow_ = wc * 64 + n * 16 + l15;
                int bcol = (kk * 4 + g) ^ (brow_ & 7);
                b[n] = *(const f16x8*)&Bs[cur][brow_ * 64 + bcol * 8];
            }
            #pragma unroll
            for (int m = 0; m < 4; ++m)
                #pragma unroll
                for (int n = 0; n < 4; ++n)
                    acc[m][n] = MFMA16(a[m], b[n], acc[m][n]);
        }
        asm volatile("s_waitcnt vmcnt(0)" ::: "memory");
        __syncthreads();
        cur ^= 1;
    }
    #undef QKV_STAGE

    // epilogue: C/D layout col = lane&15, row = (lane>>4)*4 + reg
    const int which = bn >> 2, head = bn & 3;
    f16* dst = (which == 0) ? Qp : (which == 1) ? Kp : Vp;
    #pragma unroll
    for (int m = 0; m < 4; ++m) {
        #pragma unroll
        for (int j = 0; j < 4; ++j) {
            int gm = brow + wr * 64 + m * 16 + g * 4 + j;  // token index
            size_t obase = ((size_t)(tokmap[gm] + head * 360)) * 128;
            #pragma unroll
            for (int n = 0; n < 4; ++n) {
                int cidx = wc * 64 + n * 16 + l15;
                float v = acc[m][n][j] + bias[bn * 128 + cidx];
                dst[obase + cidx] = (f16)v;
            }
        }
    }
}

// ----------------------------------------------------------- attention ----
// One block per (win, head). 8 waves x 48 q-rows (padded to 384).
__global__ __launch_bounds__(512) void attn_kernel(
    const f16* __restrict__ Qp, const f16* __restrict__ Kp,
    const f16* __restrict__ Vp, f16* __restrict__ AO)
{
    __shared__ __align__(16) f16 Kl[64 * 136];   // K tile, padded stride
    __shared__ __align__(16) f16 Vt[128 * 72];   // V tile transposed [ch][k]
    __shared__ __align__(16) f16 Pl[384 * 72];   // P round-trip [q][k]

    const int tid = threadIdx.x;
    const int lane = tid & 63, wid = tid >> 6;
    const int g = lane >> 4, l15 = lane & 15;
    const int wh = blockIdx.x;
    const int win = wh >> 2, head = wh & 3;
    const int base = wh * 46080;  // 360*128

    const float SC2 = 0.08838834764831845f * 1.4426950408889634f;  // scale*log2e

    // Q fragments in registers: 48 rows x 128 ch per wave
    f16x8 qf[3][4];
    #pragma unroll
    for (int qi = 0; qi < 3; ++qi)
        #pragma unroll
        for (int c4 = 0; c4 < 4; ++c4)
            qf[qi][c4] = *(const f16x8*)(Qp + base + (wid * 48 + qi * 16 + l15) * 128 + c4 * 32 + g * 8);

    f32x4 o[3][8] = {};
    float m_r[3] = { -1e30f, -1e30f, -1e30f };
    float l_r[3] = { 0.f, 0.f, 0.f };

    for (int kt = 0; kt < 6; ++kt) {
        // --- stage K tile [64][128] linearly (padded stride 136)
        #pragma unroll
        for (int it = 0; it < 2; ++it) {
            int idx = it * 512 + tid;
            int krow = idx >> 4, seg = idx & 15;
            f16x8 kv = *(const f16x8*)(Kp + base + (kt * 64 + krow) * 128 + seg * 8);
            *(f16x8*)&Kl[krow * 136 + seg * 8] = kv;
        }
        // --- stage V tile transposed: [ch][k], zero-fill k >= 360
        {
            const u32* Vb = (const u32*)(Vp + base);
            int chp = (tid & 63) * 2;
            int kb = wid;  // 0..7 -> k block of 8
            u32 d[8];
            #pragma unroll
            for (int i = 0; i < 8; ++i) {
                int kg = kt * 64 + kb * 8 + i;
                d[i] = (kg < 360) ? Vb[kg * 64 + (chp >> 1)] : 0u;
            }
            u32x4 lo, hi;
            #pragma unroll
            for (int jj = 0; jj < 4; ++jj) {
                lo[jj] = (d[2 * jj] & 0xffffu) | (d[2 * jj + 1] << 16);
                hi[jj] = (d[2 * jj] >> 16) | (d[2 * jj + 1] & 0xffff0000u);
            }
            *(u32x4*)&Vt[chp * 72 + kb * 8] = lo;
            *(u32x4*)&Vt[(chp + 1) * 72 + kb * 8] = hi;
        }
        __syncthreads();

        // --- S^T = K · Q^T : C[k,q], lane holds col q = lane&15, rows k = g*4+j
        f32x4 sc[4][3] = {};
        #pragma unroll
        for (int c4 = 0; c4 < 4; ++c4) {
            f16x8 ka[4];
            #pragma unroll
            for (int kf = 0; kf < 4; ++kf)
                ka[kf] = *(const f16x8*)&Kl[(kf * 16 + l15) * 136 + c4 * 32 + g * 8];
            #pragma unroll
            for (int kf = 0; kf < 4; ++kf)
                #pragma unroll
                for (int qi = 0; qi < 3; ++qi)
                    sc[kf][qi] = MFMA16(ka[kf], qf[qi][c4], sc[kf][qi]);
        }
        // mask pad keys (only last tile)
        if (kt == 5) {
            #pragma unroll
            for (int kf = 0; kf < 4; ++kf)
                #pragma unroll
                for (int j = 0; j < 4; ++j)
                    if (320 + kf * 16 + g * 4 + j >= 360) {
                        #pragma unroll
                        for (int qi = 0; qi < 3; ++qi) sc[kf][qi][j] = -1e30f;
                    }
        }

        // --- online softmax; P -> LDS
        #pragma unroll
        for (int qi = 0; qi < 3; ++qi) {
            float mx = -1e30f;
            #pragma unroll
            for (int kf = 0; kf < 4; ++kf)
                #pragma unroll
                for (int j = 0; j < 4; ++j)
                    mx = fmaxf(mx, sc[kf][qi][j]);
            mx = fmaxf(mx, __shfl_xor(mx, 16));
            mx = fmaxf(mx, __shfl_xor(mx, 32));
            float mnew = fmaxf(m_r[qi], mx);
            float r = exp2f((m_r[qi] - mnew) * SC2);
            m_r[qi] = mnew;
            float psum = 0.f;
            #pragma unroll
            for (int kf = 0; kf < 4; ++kf) {
                f16x4 pv;
                #pragma unroll
                for (int j = 0; j < 4; ++j) {
                    float p = exp2f((sc[kf][qi][j] - mnew) * SC2);
                    psum += p;
                    pv[j] = (f16)p;
                }
                *(f16x4*)&Pl[(wid * 48 + qi * 16 + l15) * 72 + kf * 16 + g * 4] = pv;
            }
            psum += __shfl_xor(psum, 16);
            psum += __shfl_xor(psum, 32);
            l_r[qi] = l_r[qi] * r + psum;
            // rescale O: r lives at lanes keyed by q=lane&15; O rows are g*4+j
            #pragma unroll
            for (int j = 0; j < 4; ++j) {
                float rj = __shfl(r, g * 4 + j);
                #pragma unroll
                for (int chf = 0; chf < 8; ++chf)
                    o[qi][chf][j] *= rj;
            }
        }

        // --- PV: O[q,ch] += P[q,k] * V[k,ch]
        #pragma unroll
        for (int kc = 0; kc < 2; ++kc) {
            f16x8 pa[3], vb[8];
            #pragma unroll
            for (int qi = 0; qi < 3; ++qi)
                pa[qi] = *(const f16x8*)&Pl[(wid * 48 + qi * 16 + l15) * 72 + kc * 32 + g * 8];
            #pragma unroll
            for (int chf = 0; chf < 8; ++chf)
                vb[chf] = *(const f16x8*)&Vt[(chf * 16 + l15) * 72 + kc * 32 + g * 8];
            #pragma unroll
            for (int qi = 0; qi < 3; ++qi)
                #pragma unroll
                for (int chf = 0; chf < 8; ++chf)
                    o[qi][chf] = MFMA16(pa[qi], vb[chf], o[qi][chf]);
        }
        __syncthreads();
    }

    // --- epilogue: normalize, un-partition, store fp16 AO[token][512]
    #pragma unroll
    for (int qi = 0; qi < 3; ++qi) {
        #pragma unroll
        for (int j = 0; j < 4; ++j) {
            float lj = __shfl(l_r[qi], g * 4 + j);
            float inv = 1.0f / lj;
            int s = wid * 48 + qi * 16 + g * 4 + j;
            if (s < 360) {
                int t_ = s / 45, s45 = s % 45;
                int hh = (win / 12) * 5 + s45 / 9;
                int ww = (win % 12) * 9 + s45 % 9;
                int mm = t_ * 6480 + hh * 108 + ww;
                #pragma unroll
                for (int chf = 0; chf < 8; ++chf) {
                    int col = head * 128 + chf * 16 + l15;
                    AO[(size_t)mm * 512 + col] = (f16)(o[qi][chf][j] * inv);
                }
            }
        }
    }
}

// ----------------------------------------------------------- out proj ----
// 1D grid 1620, bijective XCD swizzle; logical wg = bm*4 + bn.
__global__ __launch_bounds__(256) void proj_gemm(
    const f16* __restrict__ A, const f16* __restrict__ W,
    const float* __restrict__ bias, float* __restrict__ out)
{
    __shared__ __align__(16) f16 As[2][128 * 64];
    __shared__ __align__(16) f16 Bs[2][128 * 64];
    const int tid = threadIdx.x;
    const int lane = tid & 63, wid = tid >> 6;
    const int g = lane >> 4, l15 = lane & 15;
    const int wr = wid >> 1, wc = wid & 1;

    // bijective XCD chunk remap (nwg=1620, q=202, r=4)
    const int orig = blockIdx.x;
    const int xcd = orig & 7;
    const int wg = (xcd < 4 ? xcd * 203 : 812 + (xcd - 4) * 202) + (orig >> 3);
    const int bcol = (wg & 3) * 128;
    const int brow = (wg >> 2) * 128;

    const f16* Abase = A + (size_t)brow * 512;
    const f16* Bbase = W + (size_t)bcol * 512;

    f32x4 acc[4][4] = {};

    #define PROJ_STAGE(buf, step)                                             \
        {                                                                     \
            const int k0_ = (step) * 64;                                      \
            _Pragma("unroll")                                                 \
            for (int rr = 0; rr < 4; ++rr) {                                  \
                int idx = rr * 256 + tid;                                     \
                int row = idx >> 3, ch = idx & 7;                             \
                int sch = ch ^ (row & 7);                                     \
                async_copy16(&As[buf][idx * 8],                               \
                             Abase + (size_t)row * 512 + k0_ + sch * 8);      \
                async_copy16(&Bs[buf][idx * 8],                               \
                             Bbase + (size_t)row * 512 + k0_ + sch * 8);      \
            }                                                                 \
        }

    PROJ_STAGE(0, 0);
    asm volatile("s_waitcnt vmcnt(0)" ::: "memory");
    __syncthreads();

    int cur = 0;
    for (int step = 0; step < 8; ++step) {
        if (step < 7) PROJ_STAGE(cur ^ 1, step + 1);
        #pragma unroll
        for (int kk = 0; kk < 2; ++kk) {
            f16x8 a[4], b[4];
            #pragma unroll
            for (int m = 0; m < 4; ++m) {
                int arow = wr * 64 + m * 16 + l15;
                int acol = (kk * 4 + g) ^ (arow & 7);
                a[m] = *(const f16x8*)&As[cur][arow * 64 + acol * 8];
            }
            #pragma unroll
            for (int n = 0; n < 4; ++n) {
                int brow_ = wc * 64 + n * 16 + l15;
                int bcol_ = (kk * 4 + g) ^ (brow_ & 7);
                b[n] = *(const f16x8*)&Bs[cur][brow_ * 64 + bcol_ * 8];
            }
            #pragma unroll
            for (int m = 0; m < 4; ++m)
                #pragma unroll
                for (int n = 0; n < 4; ++n)
                    acc[m][n] = MFMA16(a[m], b[n], acc[m][n]);
        }
        asm volatile("s_waitcnt vmcnt(0)" ::: "memory");
        __syncthreads();
        cur ^= 1;
    }
    #undef PROJ_STAGE

    #pragma unroll
    for (int m = 0; m < 4; ++m)
        #pragma unroll
        for (int j = 0; j < 4; ++j) {
            int gm = brow + wr * 64 + m * 16 + g * 4 + j;
            #pragma unroll
            for (int n = 0; n < 4; ++n) {
                int gn = bcol + wc * 64 + n * 16 + l15;
                out[(size_t)gm * 512 + gn] = acc[m][n][j] + bias[gn];
            }
        }
}

// -------------------------------------------------------------- launch ----
extern "C" void kernel_launch(void* const* d_in, const int* in_sizes, int n_in,
                              void* d_out, int out_size, void* d_ws, size_t ws_size,
                              hipStream_t stream)
{
    (void)in_sizes; (void)n_in; (void)out_size; (void)ws_size;
    const float* x  = (const float*)d_in[0];
    const float* Wq = (const float*)d_in[1];
    const float* bq = (const float*)d_in[2];
    const float* Wk = (const float*)d_in[3];
    const float* bk = (const float*)d_in[4];
    const float* Wv = (const float*)d_in[5];
    const float* bv = (const float*)d_in[6];
    const float* Wp = (const float*)d_in[7];
    const float* bp = (const float*)d_in[8];

    // workspace layout (fp16 elems): Qp/Kp/Vp [576][360][128], AO [51840][512]
    // xh (fp16 X) aliases AO: dead before attn_kernel overwrites AO.
    f16* Qp   = (f16*)d_ws;
    f16* Kp   = Qp + 26542080;
    f16* Vp   = Kp + 26542080;
    f16* AO   = Vp + 26542080;
    f16* xh   = AO;
    f16* Wqkv = AO + 26542080;
    f16* Wph  = Wqkv + 786432;
    float* bqkv = (float*)(Wph + 262144);
    int* tokmap = (int*)(bqkv + 1536);

    prep_kernel<<<4305, 256, 0, stream>>>(Wq, Wk, Wv, Wp, bq, bk, bv, Wqkv, Wph, bqkv, tokmap);
    convert_x<<<12960, 256, 0, stream>>>(x, xh);
    qkv_gemm<<<4860, 256, 0, stream>>>(xh, Wqkv, bqkv, tokmap, Qp, Kp, Vp);
    attn_kernel<<<576, 512, 0, stream>>>(Qp, Kp, Vp, AO);
    proj_gemm<<<1620, 256, 0, stream>>>(AO, Wph, bp, (float*)d_out);
}

// Round 5
// 291.916 us; speedup vs baseline: 1.4226x; 1.0475x over previous
//
#include <hip/hip_runtime.h>

typedef _Float16 f16;
typedef _Float16 f16x8 __attribute__((ext_vector_type(8)));
typedef _Float16 f16x4 __attribute__((ext_vector_type(4)));
typedef float f32x4 __attribute__((ext_vector_type(4)));
typedef unsigned int u32;
typedef unsigned int u32x4 __attribute__((ext_vector_type(4)));

#define MFMA16(a, b, c) __builtin_amdgcn_mfma_f32_16x16x32_f16(a, b, c, 0, 0, 0)

__device__ __forceinline__ void async_copy16(f16* lds, const f16* g) {
    __builtin_amdgcn_global_load_lds(
        (const __attribute__((address_space(1))) unsigned int*)g,
        (__attribute__((address_space(3))) unsigned int*)lds,
        16, 0, 0);
}

// ---------------------------------------------------------------- prep ----
__global__ __launch_bounds__(256) void prep_kernel(
    const float* __restrict__ Wq, const float* __restrict__ Wk,
    const float* __restrict__ Wv, const float* __restrict__ Wp,
    const float* __restrict__ bq, const float* __restrict__ bk,
    const float* __restrict__ bv,
    f16* __restrict__ Wqkv, f16* __restrict__ Wph, float* __restrict__ bqkv,
    int* __restrict__ tokmap)
{
    int i = blockIdx.x * 256 + threadIdx.x;
    if (i < 786432) {
        int r = i >> 9, c = i & 511;
        const float* src = (r < 512) ? Wq : (r < 1024) ? Wk : Wv;
        Wqkv[i] = (f16)src[(r & 511) * 512 + c];
    } else if (i < 786432 + 262144) {
        int j = i - 786432;
        Wph[j] = (f16)Wp[j];
    } else if (i < 786432 + 262144 + 1536) {
        int j = i - (786432 + 262144);
        bqkv[j] = (j < 512) ? bq[j] : (j < 1024) ? bk[j - 512] : bv[j - 1024];
    } else if (i < 786432 + 262144 + 1536 + 51840) {
        int j = i - (786432 + 262144 + 1536);
        int t_ = j / 6480, rem = j % 6480;
        int hh = rem / 108, ww = rem % 108;
        int win = (hh / 5) * 12 + (ww / 9);
        int s = t_ * 45 + (hh % 5) * 9 + (ww % 9);
        tokmap[j] = win * 1440 + s;   // obase/128 (head 0)
    }
}

// ---------------------------------------------------------- convert x ----
__global__ __launch_bounds__(256) void convert_x(
    const float* __restrict__ x, f16* __restrict__ xh)
{
    int i = blockIdx.x * 256 + threadIdx.x;   // 3,317,760 total, each does 8
    f32x4 a = *(const f32x4*)(x + (size_t)i * 8);
    f32x4 b = *(const f32x4*)(x + (size_t)i * 8 + 4);
    f16x8 h = { (f16)a[0], (f16)a[1], (f16)a[2], (f16)a[3],
                (f16)b[0], (f16)b[1], (f16)b[2], (f16)b[3] };
    *(f16x8*)(xh + (size_t)i * 8) = h;
}

// ------------------------------------------------------------ QKV GEMM ----
// C[m,n] = sum_c Xh[m,c] * W[n,c] + bias[n]; scatter into partitioned Q/K/V.
// 1D grid 4860, bijective XCD swizzle; logical wg = bm*12 + bn.
// Double-buffered LDS, stage(t+1) before compute(t).
// LDS XOR-swizzle (T2, both-sides): physical 16B slot c holds logical
// slot c^(row&7); gload_lds source pre-swizzled, ds_read applies same XOR.
__global__ __launch_bounds__(256) void qkv_gemm(
    const f16* __restrict__ Xh, const f16* __restrict__ W,
    const float* __restrict__ bias, const int* __restrict__ tokmap,
    f16* __restrict__ Qp, f16* __restrict__ Kp, f16* __restrict__ Vp)
{
    __shared__ __align__(16) f16 As[2][128 * 64];
    __shared__ __align__(16) f16 Bs[2][128 * 64];
    const int tid = threadIdx.x;
    const int lane = tid & 63, wid = tid >> 6;
    const int g = lane >> 4, l15 = lane & 15;
    const int wr = wid >> 1, wc = wid & 1;

    // bijective XCD chunk remap (nwg=4860, q=607, r=4)
    const int orig = blockIdx.x;
    const int xcd = orig & 7;
    const int wg = (xcd < 4 ? xcd * 608 : 2432 + (xcd - 4) * 607) + (orig >> 3);
    const int bn = wg % 12;
    const int brow = (wg / 12) * 128;

    const f16* Abase = Xh + (size_t)brow * 512;
    const f16* Bbase = W + (size_t)bn * 128 * 512;

    f32x4 acc[4][4] = {};

    // stage: LDS dest linear (gload_lds constraint); global source slot
    // pre-swizzled so that ds_read with the same XOR sees logical layout.
    #define QKV_STAGE(buf, step)                                              \
        {                                                                     \
            const int k0_ = (step) * 64;                                      \
            _Pragma("unroll")                                                 \
            for (int rr = 0; rr < 4; ++rr) {                                  \
                int idx = rr * 256 + tid;                                     \
                int row = idx >> 3, ch = idx & 7;                             \
                int sch = ch ^ (row & 7);                                     \
                async_copy16(&As[buf][idx * 8],                               \
                             Abase + (size_t)row * 512 + k0_ + sch * 8);      \
                async_copy16(&Bs[buf][idx * 8],                               \
                             Bbase + (size_t)row * 512 + k0_ + sch * 8);      \
            }                                                                 \
        }

    QKV_STAGE(0, 0);
    asm volatile("s_waitcnt vmcnt(0)" ::: "memory");
    __syncthreads();

    int cur = 0;
    for (int step = 0; step < 8; ++step) {
        if (step < 7) QKV_STAGE(cur ^ 1, step + 1);
        #pragma unroll
        for (int kk = 0; kk < 2; ++kk) {
            f16x8 a[4], b[4];
            #pragma unroll
            for (int m = 0; m < 4; ++m) {
                int arow = wr * 64 + m * 16 + l15;
                int acol = (kk * 4 + g) ^ (arow & 7);
                a[m] = *(const f16x8*)&As[cur][arow * 64 + acol * 8];
            }
            #pragma unroll
            for (int n = 0; n < 4; ++n) {
                int brow_ = wc * 64 + n * 16 + l15;
                int bcol = (kk * 4 + g) ^ (brow_ & 7);
                b[n] = *(const f16x8*)&Bs[cur][brow_ * 64 + bcol * 8];
            }
            #pragma unroll
            for (int m = 0; m < 4; ++m)
                #pragma unroll
                for (int n = 0; n < 4; ++n)
                    acc[m][n] = MFMA16(a[m], b[n], acc[m][n]);
        }
        asm volatile("s_waitcnt vmcnt(0)" ::: "memory");
        __syncthreads();
        cur ^= 1;
    }
    #undef QKV_STAGE

    // epilogue: C/D layout col = lane&15, row = (lane>>4)*4 + reg
    const int which = bn >> 2, head = bn & 3;
    f16* dst = (which == 0) ? Qp : (which == 1) ? Kp : Vp;
    #pragma unroll
    for (int m = 0; m < 4; ++m) {
        #pragma unroll
        for (int j = 0; j < 4; ++j) {
            int gm = brow + wr * 64 + m * 16 + g * 4 + j;  // token index
            size_t obase = ((size_t)(tokmap[gm] + head * 360)) * 128;
            #pragma unroll
            for (int n = 0; n < 4; ++n) {
                int cidx = wc * 64 + n * 16 + l15;
                float v = acc[m][n][j] + bias[bn * 128 + cidx];
                dst[obase + cidx] = (f16)v;
            }
        }
    }
}

// ----------------------------------------------------------- attention ----
// Two blocks per (win, head): block covers 192 q-rows (4 waves x 48).
// LDS 63.5KB -> 2 blocks/CU; independent blocks overlap staging stalls.
__global__ __launch_bounds__(256, 2) void attn_kernel(
    const f16* __restrict__ Qp, const f16* __restrict__ Kp,
    const f16* __restrict__ Vp, f16* __restrict__ AO)
{
    __shared__ __align__(16) f16 Kl[64 * 136];   // K tile, padded stride
    __shared__ __align__(16) f16 Vt[128 * 72];   // V tile transposed [ch][k]
    __shared__ __align__(16) f16 Pl[192 * 72];   // P round-trip [q][k], 4 waves

    const int tid = threadIdx.x;
    const int lane = tid & 63, wid = tid >> 6;      // wid 0..3
    const int g = lane >> 4, l15 = lane & 15;
    const int wh = blockIdx.x >> 1;                 // win*4+head
    const int half = blockIdx.x & 1;
    const int win = wh >> 2, head = wh & 3;
    const int base = wh * 46080;                    // 360*128
    const int qbase = half * 192 + wid * 48;        // this wave's first q-row

    const float SC2 = 0.08838834764831845f * 1.4426950408889634f;  // scale*log2e

    // Q fragments in registers: 48 rows x 128 ch per wave
    f16x8 qf[3][4];
    #pragma unroll
    for (int qi = 0; qi < 3; ++qi)
        #pragma unroll
        for (int c4 = 0; c4 < 4; ++c4)
            qf[qi][c4] = *(const f16x8*)(Qp + base + (qbase + qi * 16 + l15) * 128 + c4 * 32 + g * 8);

    f32x4 o[3][8] = {};
    float m_r[3] = { -1e30f, -1e30f, -1e30f };
    float l_r[3] = { 0.f, 0.f, 0.f };

    for (int kt = 0; kt < 6; ++kt) {
        // --- stage K tile [64][128] linearly (padded stride 136), 256 thr
        #pragma unroll
        for (int it = 0; it < 4; ++it) {
            int idx = it * 256 + tid;
            int krow = idx >> 4, seg = idx & 15;
            f16x8 kv = *(const f16x8*)(Kp + base + (kt * 64 + krow) * 128 + seg * 8);
            *(f16x8*)&Kl[krow * 136 + seg * 8] = kv;
        }
        // --- stage V tile transposed: [ch][k], zero-fill k >= 360, 256 thr
        #pragma unroll
        for (int it = 0; it < 2; ++it) {
            int i2 = it * 256 + tid;               // 0..511
            int kb = i2 >> 6;                      // 0..7 -> k block of 8
            int chp = (i2 & 63) * 2;               // even channel
            const u32* Vb = (const u32*)(Vp + base);
            u32 d[8];
            #pragma unroll
            for (int i = 0; i < 8; ++i) {
                int kg = kt * 64 + kb * 8 + i;
                d[i] = (kg < 360) ? Vb[kg * 64 + (chp >> 1)] : 0u;
            }
            u32x4 lo, hi;
            #pragma unroll
            for (int jj = 0; jj < 4; ++jj) {
                lo[jj] = (d[2 * jj] & 0xffffu) | (d[2 * jj + 1] << 16);
                hi[jj] = (d[2 * jj] >> 16) | (d[2 * jj + 1] & 0xffff0000u);
            }
            *(u32x4*)&Vt[chp * 72 + kb * 8] = lo;
            *(u32x4*)&Vt[(chp + 1) * 72 + kb * 8] = hi;
        }
        __syncthreads();

        // --- S^T = K · Q^T : C[k,q], lane holds col q = lane&15, rows k = g*4+j
        f32x4 sc[4][3] = {};
        __builtin_amdgcn_s_setprio(1);
        #pragma unroll
        for (int c4 = 0; c4 < 4; ++c4) {
            f16x8 ka[4];
            #pragma unroll
            for (int kf = 0; kf < 4; ++kf)
                ka[kf] = *(const f16x8*)&Kl[(kf * 16 + l15) * 136 + c4 * 32 + g * 8];
            #pragma unroll
            for (int kf = 0; kf < 4; ++kf)
                #pragma unroll
                for (int qi = 0; qi < 3; ++qi)
                    sc[kf][qi] = MFMA16(ka[kf], qf[qi][c4], sc[kf][qi]);
        }
        __builtin_amdgcn_s_setprio(0);
        // mask pad keys (only last tile)
        if (kt == 5) {
            #pragma unroll
            for (int kf = 0; kf < 4; ++kf)
                #pragma unroll
                for (int j = 0; j < 4; ++j)
                    if (320 + kf * 16 + g * 4 + j >= 360) {
                        #pragma unroll
                        for (int qi = 0; qi < 3; ++qi) sc[kf][qi][j] = -1e30f;
                    }
        }

        // --- online softmax; P -> LDS
        #pragma unroll
        for (int qi = 0; qi < 3; ++qi) {
            float mx = -1e30f;
            #pragma unroll
            for (int kf = 0; kf < 4; ++kf)
                #pragma unroll
                for (int j = 0; j < 4; ++j)
                    mx = fmaxf(mx, sc[kf][qi][j]);
            mx = fmaxf(mx, __shfl_xor(mx, 16));
            mx = fmaxf(mx, __shfl_xor(mx, 32));
            float mnew = fmaxf(m_r[qi], mx);
            float r = exp2f((m_r[qi] - mnew) * SC2);
            m_r[qi] = mnew;
            float psum = 0.f;
            #pragma unroll
            for (int kf = 0; kf < 4; ++kf) {
                f16x4 pv;
                #pragma unroll
                for (int j = 0; j < 4; ++j) {
                    float p = exp2f((sc[kf][qi][j] - mnew) * SC2);
                    psum += p;
                    pv[j] = (f16)p;
                }
                *(f16x4*)&Pl[(wid * 48 + qi * 16 + l15) * 72 + kf * 16 + g * 4] = pv;
            }
            psum += __shfl_xor(psum, 16);
            psum += __shfl_xor(psum, 32);
            l_r[qi] = l_r[qi] * r + psum;
            // rescale O: r lives at lanes keyed by q=lane&15; O rows are g*4+j
            #pragma unroll
            for (int j = 0; j < 4; ++j) {
                float rj = __shfl(r, g * 4 + j);
                #pragma unroll
                for (int chf = 0; chf < 8; ++chf)
                    o[qi][chf][j] *= rj;
            }
        }

        // --- PV: O[q,ch] += P[q,k] * V[k,ch]
        __builtin_amdgcn_s_setprio(1);
        #pragma unroll
        for (int kc = 0; kc < 2; ++kc) {
            f16x8 pa[3], vb[8];
            #pragma unroll
            for (int qi = 0; qi < 3; ++qi)
                pa[qi] = *(const f16x8*)&Pl[(wid * 48 + qi * 16 + l15) * 72 + kc * 32 + g * 8];
            #pragma unroll
            for (int chf = 0; chf < 8; ++chf)
                vb[chf] = *(const f16x8*)&Vt[(chf * 16 + l15) * 72 + kc * 32 + g * 8];
            #pragma unroll
            for (int qi = 0; qi < 3; ++qi)
                #pragma unroll
                for (int chf = 0; chf < 8; ++chf)
                    o[qi][chf] = MFMA16(pa[qi], vb[chf], o[qi][chf]);
        }
        __builtin_amdgcn_s_setprio(0);
        __syncthreads();
    }

    // --- epilogue: normalize, un-partition, store fp16 AO[token][512]
    #pragma unroll
    for (int qi = 0; qi < 3; ++qi) {
        #pragma unroll
        for (int j = 0; j < 4; ++j) {
            float lj = __shfl(l_r[qi], g * 4 + j);
            float inv = 1.0f / lj;
            int s = qbase + qi * 16 + g * 4 + j;
            if (s < 360) {
                int t_ = s / 45, s45 = s % 45;
                int hh = (win / 12) * 5 + s45 / 9;
                int ww = (win % 12) * 9 + s45 % 9;
                int mm = t_ * 6480 + hh * 108 + ww;
                #pragma unroll
                for (int chf = 0; chf < 8; ++chf) {
                    int col = head * 128 + chf * 16 + l15;
                    AO[(size_t)mm * 512 + col] = (f16)(o[qi][chf][j] * inv);
                }
            }
        }
    }
}

// ----------------------------------------------------------- out proj ----
// 1D grid 1620, bijective XCD swizzle; logical wg = bm*4 + bn.
__global__ __launch_bounds__(256) void proj_gemm(
    const f16* __restrict__ A, const f16* __restrict__ W,
    const float* __restrict__ bias, float* __restrict__ out)
{
    __shared__ __align__(16) f16 As[2][128 * 64];
    __shared__ __align__(16) f16 Bs[2][128 * 64];
    const int tid = threadIdx.x;
    const int lane = tid & 63, wid = tid >> 6;
    const int g = lane >> 4, l15 = lane & 15;
    const int wr = wid >> 1, wc = wid & 1;

    // bijective XCD chunk remap (nwg=1620, q=202, r=4)
    const int orig = blockIdx.x;
    const int xcd = orig & 7;
    const int wg = (xcd < 4 ? xcd * 203 : 812 + (xcd - 4) * 202) + (orig >> 3);
    const int bcol = (wg & 3) * 128;
    const int brow = (wg >> 2) * 128;

    const f16* Abase = A + (size_t)brow * 512;
    const f16* Bbase = W + (size_t)bcol * 512;

    f32x4 acc[4][4] = {};

    #define PROJ_STAGE(buf, step)                                             \
        {                                                                     \
            const int k0_ = (step) * 64;                                      \
            _Pragma("unroll")                                                 \
            for (int rr = 0; rr < 4; ++rr) {                                  \
                int idx = rr * 256 + tid;                                     \
                int row = idx >> 3, ch = idx & 7;                             \
                int sch = ch ^ (row & 7);                                     \
                async_copy16(&As[buf][idx * 8],                               \
                             Abase + (size_t)row * 512 + k0_ + sch * 8);      \
                async_copy16(&Bs[buf][idx * 8],                               \
                             Bbase + (size_t)row * 512 + k0_ + sch * 8);      \
            }                                                                 \
        }

    PROJ_STAGE(0, 0);
    asm volatile("s_waitcnt vmcnt(0)" ::: "memory");
    __syncthreads();

    int cur = 0;
    for (int step = 0; step < 8; ++step) {
        if (step < 7) PROJ_STAGE(cur ^ 1, step + 1);
        #pragma unroll
        for (int kk = 0; kk < 2; ++kk) {
            f16x8 a[4], b[4];
            #pragma unroll
            for (int m = 0; m < 4; ++m) {
                int arow = wr * 64 + m * 16 + l15;
                int acol = (kk * 4 + g) ^ (arow & 7);
                a[m] = *(const f16x8*)&As[cur][arow * 64 + acol * 8];
            }
            #pragma unroll
            for (int n = 0; n < 4; ++n) {
                int brow_ = wc * 64 + n * 16 + l15;
                int bcol_ = (kk * 4 + g) ^ (brow_ & 7);
                b[n] = *(const f16x8*)&Bs[cur][brow_ * 64 + bcol_ * 8];
            }
            #pragma unroll
            for (int m = 0; m < 4; ++m)
                #pragma unroll
                for (int n = 0; n < 4; ++n)
                    acc[m][n] = MFMA16(a[m], b[n], acc[m][n]);
        }
        asm volatile("s_waitcnt vmcnt(0)" ::: "memory");
        __syncthreads();
        cur ^= 1;
    }
    #undef PROJ_STAGE

    #pragma unroll
    for (int m = 0; m < 4; ++m)
        #pragma unroll
        for (int j = 0; j < 4; ++j) {
            int gm = brow + wr * 64 + m * 16 + g * 4 + j;
            #pragma unroll
            for (int n = 0; n < 4; ++n) {
                int gn = bcol + wc * 64 + n * 16 + l15;
                out[(size_t)gm * 512 + gn] = acc[m][n][j] + bias[gn];
            }
        }
}

// -------------------------------------------------------------- launch ----
extern "C" void kernel_launch(void* const* d_in, const int* in_sizes, int n_in,
                              void* d_out, int out_size, void* d_ws, size_t ws_size,
                              hipStream_t stream)
{
    (void)in_sizes; (void)n_in; (void)out_size; (void)ws_size;
    const float* x  = (const float*)d_in[0];
    const float* Wq = (const float*)d_in[1];
    const float* bq = (const float*)d_in[2];
    const float* Wk = (const float*)d_in[3];
    const float* bk = (const float*)d_in[4];
    const float* Wv = (const float*)d_in[5];
    const float* bv = (const float*)d_in[6];
    const float* Wp = (const float*)d_in[7];
    const float* bp = (const float*)d_in[8];

    // workspace layout (fp16 elems): Qp/Kp/Vp [576][360][128], AO [51840][512]
    // xh (fp16 X) aliases AO: dead before attn_kernel overwrites AO.
    f16* Qp   = (f16*)d_ws;
    f16* Kp   = Qp + 26542080;
    f16* Vp   = Kp + 26542080;
    f16* AO   = Vp + 26542080;
    f16* xh   = AO;
    f16* Wqkv = AO + 26542080;
    f16* Wph  = Wqkv + 786432;
    float* bqkv = (float*)(Wph + 262144);
    int* tokmap = (int*)(bqkv + 1536);

    prep_kernel<<<4305, 256, 0, stream>>>(Wq, Wk, Wv, Wp, bq, bk, bv, Wqkv, Wph, bqkv, tokmap);
    convert_x<<<12960, 256, 0, stream>>>(x, xh);
    qkv_gemm<<<4860, 256, 0, stream>>>(xh, Wqkv, bqkv, tokmap, Qp, Kp, Vp);
    attn_kernel<<<1152, 256, 0, stream>>>(Qp, Kp, Vp, AO);
    proj_gemm<<<1620, 256, 0, stream>>>(AO, Wph, bp, (float*)d_out);
}